// Round 14
// baseline (623.721 us; speedup 1.0000x reference)
//
#include <hip/hip_runtime.h>

typedef __bf16 bf16x8 __attribute__((ext_vector_type(8)));
typedef float f32x4 __attribute__((ext_vector_type(4)));
typedef unsigned short ushort8 __attribute__((ext_vector_type(8)));

__device__ __forceinline__ unsigned short f2bf(float f) {
  unsigned int u = __builtin_bit_cast(unsigned int, f);
  u += 0x7FFFu + ((u >> 16) & 1u);   // RNE
  return (unsigned short)(u >> 16);
}

__constant__ float COEF[2][3][3] = {
    {{0.25f, 0.00f, 0.00f},
     {0.75f, 0.75f, 0.25f},
     {0.00f, 0.25f, 0.75f}},
    {{0.75f, 0.25f, 0.00f},
     {0.25f, 0.75f, 0.75f},
     {0.00f, 0.00f, 0.25f}}
};

// Pack phase-blended weights into MFMA B-fragment layout, bf16 (R8 layout).
__global__ void pack_weights(const float* __restrict__ w, unsigned short* __restrict__ pw) {
  const int kt = blockIdx.x >> 3, nt = blockIdx.x & 7;
  const int l = threadIdx.x;
  const int tap = kt >> 2, cblk = kt & 3;
  const int du = tap / 3, dv = tap - du * 3;
  const int c0 = cblk * 32 + ((l >> 4) << 3);
  const int oc = nt * 16 + (l & 15);
  float accp[4][8];
#pragma unroll
  for (int ph = 0; ph < 4; ++ph)
#pragma unroll
    for (int j = 0; j < 8; ++j) accp[ph][j] = 0.0f;
#pragma unroll
  for (int u = 0; u < 3; ++u)
#pragma unroll
    for (int v = 0; v < 3; ++v) {
      const float ra0 = COEF[0][du][u], ra1 = COEF[1][du][u];
      const float cb0 = COEF[0][dv][v], cb1 = COEF[1][dv][v];
      const float c00 = ra0 * cb0, c01 = ra0 * cb1, c10 = ra1 * cb0, c11 = ra1 * cb1;
#pragma unroll
      for (int j = 0; j < 8; ++j) {
        const float wv = w[((u * 3 + v) * 128 + c0 + j) * 128 + oc];
        accp[0][j] += c00 * wv;
        accp[1][j] += c01 * wv;
        accp[2][j] += c10 * wv;
        accp[3][j] += c11 * wv;
      }
    }
  const int fi = ((cblk * 3 + dv) * 3 + du) * 8 + nt;  // 0..287
#pragma unroll
  for (int ph = 0; ph < 4; ++ph) {
    ushort8 o;
#pragma unroll
    for (int j = 0; j < 8; ++j) o[j] = f2bf(accp[ph][j]);
    *(ushort8*)(pw + (((ph * 288 + fi) * 64 + l) << 3)) = o;
  }
}

// ======================= SHARED PROBE MACROS =======================
#define PROBE_PROLOG(NWAVES)                                          \
  __shared__ __align__(16) char xlds[11 * 19 * 256];                  \
  const int o = blockIdx.x;                                           \
  const int blk = (o & 7) * 128 + (o >> 3);                           \
  const int bimg = blk >> 7;                                          \
  const int it = (blk >> 3) & 15;                                     \
  const int jt = blk & 7;                                             \
  const int I0 = it * 8, J0 = jt * 16;                                \
  const int tid = threadIdx.x;                                        \
  const float* xb = x + bimg * (128 * 128 * 128);                     \
  const int lane = tid & 63;                                          \
  const int l15 = lane & 15;                                          \
  const int lh = lane >> 4;                                           \
  const int wid = tid >> 6;                                           \
  const int a = (wid >> 2) & 1;                                       \
  const int b = (wid >> 1) & 1;                                       \
  const int nhalf = wid & 1;                                          \
  const int ph = a * 2 + b;                                           \
  const char* pwb = (const char*)pw + ph * 294912 + nhalf * 4096 + lane * 16;

#define LOADB(buf, g_, du_)                                           \
  do {                                                                \
    const char* bp_ = pwb + (((g_) * 3 + (du_)) << 13);               \
    _Pragma("unroll") for (int n = 0; n < 4; ++n)                     \
        buf[n] = *(const bf16x8*)(bp_ + n * 1024);                    \
  } while (0)

#define STAGE_R8()                                                            \
  do {                                                                        \
    for (int idx = tid; idx < 11 * 19 * 16; idx += 512) {                     \
      const int cp = idx & 15;                                                \
      const int pos = idx >> 4;                                               \
      const int xr = pos / 19;                                                \
      const int xc = pos - xr * 19;                                           \
      const int gi = I0 - 1 + xr;                                             \
      const int gj = J0 - 1 + xc;                                             \
      ushort8 u8 = {};                                                        \
      if (((unsigned)gi < 128u) && ((unsigned)gj < 128u)) {                   \
        const float* p = xb + ((gi << 7) + gj) * 128 + (cp << 3);             \
        const float4 A = *(const float4*)p;                                   \
        const float4 Bv = *(const float4*)(p + 4);                            \
        u8[0] = f2bf(A.x); u8[1] = f2bf(A.y); u8[2] = f2bf(A.z);              \
        u8[3] = f2bf(A.w); u8[4] = f2bf(Bv.x); u8[5] = f2bf(Bv.y);            \
        u8[6] = f2bf(Bv.z); u8[7] = f2bf(Bv.w);                               \
      }                                                                       \
      int byte = (pos << 8) + (cp << 4);                                      \
      byte ^= (pos & 7) << 4;                                                 \
      *(ushort8*)(xlds + byte) = u8;                                          \
    }                                                                         \
  } while (0)

#define AREADP(rr)                                                    \
    do {                                                              \
      const int posa = pbase + (rr) * 19;                             \
      int byte_ = (posa << 8) + kbyte;                                \
      byte_ ^= (posa & 7) << 4;                                       \
      af[rr] = *(const bf16x8*)(xlds + byte_);                        \
    } while (0)

#define MFMASP(du_, buf)                                              \
  do {                                                                \
    __builtin_amdgcn_s_setprio(1);                                    \
    _Pragma("unroll") for (int m = 0; m < 8; ++m)                     \
        _Pragma("unroll") for (int n = 0; n < 4; ++n)                 \
            acc[m][n] = __builtin_amdgcn_mfma_f32_16x16x32_bf16(      \
                af[(du_) + m], buf[n], acc[m][n], 0, 0, 0);           \
    __builtin_amdgcn_s_setprio(0);                                    \
  } while (0)

#define PROBE_EPILOG()                                                \
  do {                                                                \
    f32x4 s = {0.f, 0.f, 0.f, 0.f};                                   \
    _Pragma("unroll") for (int m = 0; m < 8; ++m)                     \
        _Pragma("unroll") for (int n = 0; n < 4; ++n) s += acc[m][n]; \
    *(f32x4*)(pws + ((blockIdx.x * 512 + tid) << 2)) = s;             \
  } while (0)

// Probe A: full K-loop (AREAD + LOADB + MFMA), REP=2, no out stores.
__global__ __launch_bounds__(512, 2) void probeA(
    const float* __restrict__ x, const unsigned short* __restrict__ pw,
    float* __restrict__ pws) {
  PROBE_PROLOG(8)
  bf16x8 b0[4], b1[4], b2[4];
  LOADB(b0, 0, 0);
  STAGE_R8();
  __syncthreads();
  f32x4 acc[8][4] = {};
  const int colpart = l15 + b;
#pragma unroll 1
  for (int rep = 0; rep < 2; ++rep) {
#pragma unroll 1
    for (int g = 0; g < 12; ++g) {
      const int cblk = (g * 11) >> 5;
      const int dv = g - cblk * 3;
      const int kbyte = (cblk * 4 + lh) << 4;
      const int pbase = a * 19 + colpart + dv;
      bf16x8 af[10];
      AREADP(0); AREADP(1); AREADP(2); AREADP(3);
      AREADP(4); AREADP(5); AREADP(6); AREADP(7);
      LOADB(b1, g, 1);
      AREADP(8); AREADP(9);
      LOADB(b2, g, 2);
      MFMASP(0, b0);
      {
        const int gn = (g < 11) ? (g + 1) : 0;  // wrap for rep continuity
        LOADB(b0, gn, 0);
      }
      MFMASP(1, b1);
      MFMASP(2, b2);
    }
  }
  PROBE_EPILOG();
}

// Probe B: MFMA-only. Operands loaded once; REP=3 x 36 clusters (same setprio).
__global__ __launch_bounds__(512, 2) void probeB(
    const float* __restrict__ x, const unsigned short* __restrict__ pw,
    float* __restrict__ pws) {
  PROBE_PROLOG(8)
  bf16x8 b0[4], b1[4], b2[4];
  LOADB(b0, 0, 0);
  STAGE_R8();
  __syncthreads();
  f32x4 acc[8][4] = {};
  const int colpart = l15 + b;
  bf16x8 af[10];
  {
    const int kbyte = lh << 4;
    const int pbase = a * 19 + colpart;
    AREADP(0); AREADP(1); AREADP(2); AREADP(3);
    AREADP(4); AREADP(5); AREADP(6); AREADP(7);
    AREADP(8); AREADP(9);
  }
  LOADB(b1, 0, 1);
  LOADB(b2, 0, 2);
#pragma unroll 1
  for (int rep = 0; rep < 3; ++rep) {
#pragma unroll 1
    for (int g = 0; g < 12; ++g) {
      MFMASP(0, b0);
      MFMASP(1, b1);
      MFMASP(2, b2);
    }
  }
  PROBE_EPILOG();
}

// ======================= REAL KERNEL (R8 verbatim, 172 us) =======================
__global__ __launch_bounds__(512, 2) void fused_all(
    const float* __restrict__ x, const unsigned short* __restrict__ pw,
    const float* __restrict__ w, const float* __restrict__ bias,
    float* __restrict__ out) {
  __shared__ __align__(16) char smem[11 * 19 * 256];

  const int bid = blockIdx.x;
  const int tid = threadIdx.x;

  if (bid < 512) {
    const int chunk = bid & 31;
    const int type = (bid >> 5) & 1;
    const int bi = bid >> 6;
    const int base0 = chunk * 8;
    const float* xb = x + bi * (128 * 128 * 128);
    float* yw = (float*)smem;
    float* part = (float*)(smem + 16384);
    {
      const int c = tid & 127;
      const int sub = tid >> 7;
      for (int k = sub; k < 20; k += 4) {
        const int f = k / 10;
        const int ws = k - f * 10;
        const int t = base0 - 1 + ws;
        float val = 0.0f;
        if ((unsigned)t < 256u) {
          const int t0 = t >> 1;
          const float hA0 = (t & 1) ? 0.25f : 0.75f;
          const float hA1 = 1.0f - hA0;
          const float hF0 = f ? 0.25f : 0.75f;
          const float hF1 = 1.0f - hF0;
          const bool ok = (t0 + 1) < 128;
          if (type == 0) {
            const float v00 = xb[t0 * 128 + c];
            const float v01 = ok ? xb[(t0 + 1) * 128 + c] : 0.0f;
            const float v10 = xb[(128 + t0) * 128 + c];
            const float v11 = ok ? xb[(128 + t0 + 1) * 128 + c] : 0.0f;
            val = hF0 * (hA0 * v00 + hA1 * v01) + hF1 * (hA0 * v10 + hA1 * v11);
          } else {
            const float v00 = xb[(t0 * 128) * 128 + c];
            const float v01 = xb[(t0 * 128 + 1) * 128 + c];
            const float v10 = ok ? xb[((t0 + 1) * 128) * 128 + c] : 0.0f;
            const float v11 = ok ? xb[((t0 + 1) * 128 + 1) * 128 + c] : 0.0f;
            val = hA0 * (hF0 * v00 + hF1 * v01) + hA1 * (hF0 * v10 + hF1 * v11);
          }
        }
        yw[(f * 10 + ws) * 128 + c] = val;
      }
    }
    __syncthreads();
    const int wv = tid >> 6;
    const int oc0 = (tid & 63) * 2;
    const int cbase = wv * 16;
    float acc[8][2] = {};
#pragma unroll 1
    for (int cc = 0; cc < 16; ++cc) {
      float yr[2][10];
#pragma unroll
      for (int f = 0; f < 2; ++f)
#pragma unroll
        for (int ws = 0; ws < 10; ++ws)
          yr[f][ws] = yw[(f * 10 + ws) * 128 + cbase + cc];
#pragma unroll
      for (int tf = 0; tf < 2; ++tf) {
#pragma unroll
        for (int tb = 0; tb < 3; ++tb) {
          const int uu = (type == 0) ? (tf + 1) : tb;
          const int vv = (type == 0) ? tb : (tf + 1);
          const float2 w2 = *(const float2*)(
              w + ((uu * 3 + vv) * 128 + cbase + cc) * 128 + oc0);
#pragma unroll
          for (int pos = 0; pos < 8; ++pos) {
            const float yv = yr[tf][pos + tb];
            acc[pos][0] += yv * w2.x;
            acc[pos][1] += yv * w2.y;
          }
        }
      }
    }
#pragma unroll
    for (int pos = 0; pos < 8; ++pos)
      *(float2*)(part + (wv * 8 + pos) * 128 + oc0) = *(float2*)acc[pos];
    __syncthreads();
    const int pos = tid >> 6;
    const int ocp = (tid & 63) * 2;
    float s0 = 0.0f, s1 = 0.0f;
#pragma unroll
    for (int w8 = 0; w8 < 8; ++w8) {
      const float2 v = *(const float2*)(part + (w8 * 8 + pos) * 128 + ocp);
      s0 += v.x; s1 += v.y;
    }
    const int posg = base0 + pos;
    if (!(type == 1 && posg == 0)) {
      const int p = (type == 0) ? 0 : posg;
      const int q = (type == 0) ? posg : 0;
      const float2 b2 = *(const float2*)(bias + ocp);
      float2 r; r.x = s0 + b2.x; r.y = s1 + b2.y;
      *(float2*)(out + bi * (256 * 256 * 128) + (p * 256 + q) * 128 + ocp) = r;
    }
    return;
  }

  char* xlds = smem;
  const int o = bid - 512;
  const int blk = (o & 7) * 128 + (o >> 3);
  const int bimg = blk >> 7;
  const int it = (blk >> 3) & 15;
  const int jt = blk & 7;
  const int I0 = it * 8, J0 = jt * 16;
  const float* xb = x + bimg * (128 * 128 * 128);
  const int lane = tid & 63;
  const int l15 = lane & 15;
  const int lh = lane >> 4;
  const int wid = tid >> 6;
  const int a = (wid >> 2) & 1;
  const int b = (wid >> 1) & 1;
  const int nhalf = wid & 1;
  const int ph = a * 2 + b;
  const char* pwb = (const char*)pw + ph * 294912 + nhalf * 4096 + lane * 16;

  bf16x8 b0[4], b1[4], b2[4];
  LOADB(b0, 0, 0);
  for (int idx = tid; idx < 11 * 19 * 16; idx += 512) {
    const int cp = idx & 15;
    const int pos = idx >> 4;
    const int xr = pos / 19;
    const int xc = pos - xr * 19;
    const int gi = I0 - 1 + xr;
    const int gj = J0 - 1 + xc;
    ushort8 u8 = {};
    if (((unsigned)gi < 128u) && ((unsigned)gj < 128u)) {
      const float* p = xb + ((gi << 7) + gj) * 128 + (cp << 3);
      const float4 A = *(const float4*)p;
      const float4 Bv = *(const float4*)(p + 4);
      u8[0] = f2bf(A.x); u8[1] = f2bf(A.y); u8[2] = f2bf(A.z); u8[3] = f2bf(A.w);
      u8[4] = f2bf(Bv.x); u8[5] = f2bf(Bv.y); u8[6] = f2bf(Bv.z); u8[7] = f2bf(Bv.w);
    }
    int byte = (pos << 8) + (cp << 4);
    byte ^= (pos & 7) << 4;
    *(ushort8*)(xlds + byte) = u8;
  }
  __syncthreads();
  f32x4 acc[8][4] = {};
  const int colpart = l15 + b;
#pragma unroll 1
  for (int g = 0; g < 12; ++g) {
    const int cblk = (g * 11) >> 5;
    const int dv = g - cblk * 3;
    const int kbyte = (cblk * 4 + lh) << 4;
    const int pbase = a * 19 + colpart + dv;
    bf16x8 af[10];
    AREADP(0); AREADP(1); AREADP(2); AREADP(3);
    AREADP(4); AREADP(5); AREADP(6); AREADP(7);
    LOADB(b1, g, 1);
    AREADP(8); AREADP(9);
    LOADB(b2, g, 2);
    MFMASP(0, b0);
    {
      const int gn = (g < 11) ? (g + 1) : 11;
      LOADB(b0, gn, 0);
    }
    MFMASP(1, b1);
    MFMASP(2, b2);
  }
  float bv[4];
#pragma unroll
  for (int n = 0; n < 4; ++n) bv[n] = bias[nhalf * 64 + n * 16 + l15];
  float* ob = out + bimg * (256 * 256 * 128) + nhalf * 64 + l15;
#pragma unroll
  for (int m = 0; m < 8; ++m) {
    const int p = it * 16 + 2 * m + a;
    if (p == 0) continue;
#pragma unroll
    for (int jr = 0; jr < 4; ++jr) {
      const int q = jt * 32 + 2 * (lh * 4 + jr) + b;
      if (q == 0) continue;
      float* orow = ob + (p * 256 + q) * 128;
#pragma unroll
      for (int n = 0; n < 4; ++n) orow[n * 16] = acc[m][n][jr] + bv[n];
    }
  }
}

extern "C" void kernel_launch(void* const* d_in, const int* in_sizes, int n_in,
                              void* d_out, int out_size, void* d_ws, size_t ws_size,
                              hipStream_t stream) {
  const float* x = (const float*)d_in[0];
  const float* w = (const float*)d_in[1];
  const float* bias = (const float*)d_in[2];
  float* out = (float*)d_out;
  unsigned short* pw = (unsigned short*)d_ws;                 // 1,179,648 B
  float* pws = (float*)((char*)d_ws + (2 << 20));             // 8 MB probe scratch

  pack_weights<<<dim3(288), dim3(64), 0, stream>>>(w, pw);
  if (ws_size >= (2u << 20) + (8u << 20) + 64u) {
    probeA<<<dim3(1024), dim3(512), 0, stream>>>(x, pw, pws);
    probeB<<<dim3(1024), dim3(512), 0, stream>>>(x, pw, pws);
  }
  fused_all<<<dim3(1536), dim3(512), 0, stream>>>(x, pw, w, bias, out);
}

// Round 15
// 169.687 us; speedup vs baseline: 3.6757x; 3.6757x over previous
//
#include <hip/hip_runtime.h>

typedef __bf16 bf16x8 __attribute__((ext_vector_type(8)));
typedef float f32x4 __attribute__((ext_vector_type(4)));
typedef unsigned short ushort8 __attribute__((ext_vector_type(8)));

__device__ __forceinline__ unsigned short f2bf(float f) {
  unsigned int u = __builtin_bit_cast(unsigned int, f);
  u += 0x7FFFu + ((u >> 16) & 1u);   // RNE
  return (unsigned short)(u >> 16);
}

__constant__ float COEF[2][3][3] = {
    {{0.25f, 0.00f, 0.00f},
     {0.75f, 0.75f, 0.25f},
     {0.00f, 0.25f, 0.75f}},
    {{0.75f, 0.25f, 0.00f},
     {0.25f, 0.75f, 0.75f},
     {0.00f, 0.00f, 0.25f}}
};

// Pack phase-blended weights into MFMA B-fragment layout, bf16 (R8 layout).
__global__ void pack_weights(const float* __restrict__ w, unsigned short* __restrict__ pw) {
  const int kt = blockIdx.x >> 3, nt = blockIdx.x & 7;
  const int l = threadIdx.x;
  const int tap = kt >> 2, cblk = kt & 3;
  const int du = tap / 3, dv = tap - du * 3;
  const int c0 = cblk * 32 + ((l >> 4) << 3);
  const int oc = nt * 16 + (l & 15);
  float accp[4][8];
#pragma unroll
  for (int ph = 0; ph < 4; ++ph)
#pragma unroll
    for (int j = 0; j < 8; ++j) accp[ph][j] = 0.0f;
#pragma unroll
  for (int u = 0; u < 3; ++u)
#pragma unroll
    for (int v = 0; v < 3; ++v) {
      const float ra0 = COEF[0][du][u], ra1 = COEF[1][du][u];
      const float cb0 = COEF[0][dv][v], cb1 = COEF[1][dv][v];
      const float c00 = ra0 * cb0, c01 = ra0 * cb1, c10 = ra1 * cb0, c11 = ra1 * cb1;
#pragma unroll
      for (int j = 0; j < 8; ++j) {
        const float wv = w[((u * 3 + v) * 128 + c0 + j) * 128 + oc];
        accp[0][j] += c00 * wv;
        accp[1][j] += c01 * wv;
        accp[2][j] += c10 * wv;
        accp[3][j] += c11 * wv;
      }
    }
  const int fi = ((cblk * 3 + dv) * 3 + du) * 8 + nt;  // 0..287
#pragma unroll
  for (int ph = 0; ph < 4; ++ph) {
    ushort8 o;
#pragma unroll
    for (int j = 0; j < 8; ++j) o[j] = f2bf(accp[ph][j]);
    *(ushort8*)(pw + (((ph * 288 + fi) * 64 + l) << 3)) = o;
  }
}

// Single dispatch: blocks 0..255 = persistent main (4 jt-tiles each);
// blocks 256..767 = border fixup (fill the store-drain tail).
__global__ __launch_bounds__(512, 2) void fused_all(
    const float* __restrict__ x, const unsigned short* __restrict__ pw,
    const float* __restrict__ w, const float* __restrict__ bias,
    float* __restrict__ out) {
  __shared__ __align__(16) char smem[11 * 19 * 256];  // 53,504 B

  const int bid = blockIdx.x;
  const int tid = threadIdx.x;

  if (bid >= 256) {
    // ================= BORDER PATH (R8 verbatim) =================
    const int bb = bid - 256;
    const int chunk = bb & 31;
    const int type = (bb >> 5) & 1;  // 0: row p=0 (all q); 1: col q=0 (p>=1)
    const int bi = bb >> 6;
    const int base0 = chunk * 8;
    const float* xb = x + bi * (128 * 128 * 128);

    float* yw = (float*)smem;                    // [2][10][128]
    float* part = (float*)(smem + 16384);        // [8][8][128]

    {
      const int c = tid & 127;
      const int sub = tid >> 7;  // 0..3
      for (int k = sub; k < 20; k += 4) {
        const int f = k / 10;
        const int ws = k - f * 10;
        const int t = base0 - 1 + ws;
        float val = 0.0f;
        if ((unsigned)t < 256u) {
          const int t0 = t >> 1;
          const float hA0 = (t & 1) ? 0.25f : 0.75f;
          const float hA1 = 1.0f - hA0;
          const float hF0 = f ? 0.25f : 0.75f;
          const float hF1 = 1.0f - hF0;
          const bool ok = (t0 + 1) < 128;
          if (type == 0) {
            const float v00 = xb[t0 * 128 + c];
            const float v01 = ok ? xb[(t0 + 1) * 128 + c] : 0.0f;
            const float v10 = xb[(128 + t0) * 128 + c];
            const float v11 = ok ? xb[(128 + t0 + 1) * 128 + c] : 0.0f;
            val = hF0 * (hA0 * v00 + hA1 * v01) + hF1 * (hA0 * v10 + hA1 * v11);
          } else {
            const float v00 = xb[(t0 * 128) * 128 + c];
            const float v01 = xb[(t0 * 128 + 1) * 128 + c];
            const float v10 = ok ? xb[((t0 + 1) * 128) * 128 + c] : 0.0f;
            const float v11 = ok ? xb[((t0 + 1) * 128 + 1) * 128 + c] : 0.0f;
            val = hA0 * (hF0 * v00 + hF1 * v01) + hA1 * (hF0 * v10 + hF1 * v11);
          }
        }
        yw[(f * 10 + ws) * 128 + c] = val;
      }
    }
    __syncthreads();

    const int wv = tid >> 6;
    const int oc0 = (tid & 63) * 2;
    const int cbase = wv * 16;

    float acc[8][2] = {};
#pragma unroll 1
    for (int cc = 0; cc < 16; ++cc) {
      float yr[2][10];
#pragma unroll
      for (int f = 0; f < 2; ++f)
#pragma unroll
        for (int ws = 0; ws < 10; ++ws)
          yr[f][ws] = yw[(f * 10 + ws) * 128 + cbase + cc];
#pragma unroll
      for (int tf = 0; tf < 2; ++tf) {
#pragma unroll
        for (int tb = 0; tb < 3; ++tb) {
          const int uu = (type == 0) ? (tf + 1) : tb;
          const int vv = (type == 0) ? tb : (tf + 1);
          const float2 w2 = *(const float2*)(
              w + ((uu * 3 + vv) * 128 + cbase + cc) * 128 + oc0);
#pragma unroll
          for (int pos = 0; pos < 8; ++pos) {
            const float yv = yr[tf][pos + tb];
            acc[pos][0] += yv * w2.x;
            acc[pos][1] += yv * w2.y;
          }
        }
      }
    }

#pragma unroll
    for (int pos = 0; pos < 8; ++pos)
      *(float2*)(part + (wv * 8 + pos) * 128 + oc0) = *(float2*)acc[pos];
    __syncthreads();

    const int pos = tid >> 6;
    const int ocp = (tid & 63) * 2;
    float s0 = 0.0f, s1 = 0.0f;
#pragma unroll
    for (int w8 = 0; w8 < 8; ++w8) {
      const float2 v = *(const float2*)(part + (w8 * 8 + pos) * 128 + ocp);
      s0 += v.x; s1 += v.y;
    }
    const int posg = base0 + pos;
    if (!(type == 1 && posg == 0)) {
      const int p = (type == 0) ? 0 : posg;
      const int q = (type == 0) ? posg : 0;
      const float2 b2 = *(const float2*)(bias + ocp);
      float2 r; r.x = s0 + b2.x; r.y = s1 + b2.y;
      *(float2*)(out + bi * (256 * 256 * 128) + (p * 256 + q) * 128 + ocp) = r;
    }
    return;
  }

  // ================= MAIN PATH (persistent over 4 jt-tiles) =================
  char* xlds = smem;
  const int o = bid;
  const int blk = (o & 7) * 32 + (o >> 3);  // bijective XCD swizzle (256 % 8 == 0)
  const int bimg = blk >> 5;       // 8 images
  const int it = (blk >> 1) & 15;  // 16 row-tiles of 16 out rows
  const int jh = blk & 1;          // jt half: tiles jt = jh*4 + t
  const int I0 = it * 8;
  const float* xb = x + bimg * (128 * 128 * 128);

  const int lane = tid & 63;
  const int l15 = lane & 15;
  const int lh = lane >> 4;
  const int wid = tid >> 6;
  const int a = (wid >> 2) & 1;
  const int b = (wid >> 1) & 1;
  const int nhalf = wid & 1;
  const int ph = a * 2 + b;

  const char* pwb = (const char*)pw + ph * 294912 + nhalf * 4096 + lane * 16;

#define LOADB(buf, g_, du_)                                           \
  do {                                                                \
    const char* bp_ = pwb + (((g_) * 3 + (du_)) << 13);               \
    _Pragma("unroll") for (int n = 0; n < 4; ++n)                     \
        buf[n] = *(const bf16x8*)(bp_ + n * 1024);                    \
  } while (0)

#define AREADP(rr)                                                    \
    do {                                                              \
      const int posa = pbase + (rr) * 19;                             \
      int byte_ = (posa << 8) + kbyte;                                \
      byte_ ^= (posa & 7) << 4;                                       \
      af[rr] = *(const bf16x8*)(xlds + byte_);                        \
    } while (0)

#define MFMASP(du_, buf)                                              \
  do {                                                                \
    __builtin_amdgcn_s_setprio(1);                                    \
    _Pragma("unroll") for (int m = 0; m < 8; ++m)                     \
        _Pragma("unroll") for (int n = 0; n < 4; ++n)                 \
            acc[m][n] = __builtin_amdgcn_mfma_f32_16x16x32_bf16(      \
                af[(du_) + m], buf[n], acc[m][n], 0, 0, 0);           \
    __builtin_amdgcn_s_setprio(0);                                    \
  } while (0)

  bf16x8 b0[4], b1[4], b2[4];
  LOADB(b0, 0, 0);  // prologue prefetch; completes under the first stage barrier

  float bv[4];
#pragma unroll
  for (int n = 0; n < 4; ++n) bv[n] = bias[nhalf * 64 + n * 16 + l15];
  float* ob = out + bimg * (256 * 256 * 128) + nhalf * 64 + l15;
  const int colpart = l15 + b;

  f32x4 acc[8][4] = {};

#pragma unroll 1
  for (int t = 0; t < 4; ++t) {
    const int jt = jh * 4 + t;
    const int J0 = jt * 16;

    if (t > 0) __syncthreads();  // prev K-loop's LDS reads done (also drains prev stores)

    // ---- Stage x tile: rows I0-1..I0+9, cols J0-1..J0+17, f2bf, swizzled ----
    for (int idx = tid; idx < 11 * 19 * 16; idx += 512) {
      const int cp = idx & 15;
      const int pos = idx >> 4;
      const int xr = pos / 19;
      const int xc = pos - xr * 19;
      const int gi = I0 - 1 + xr;
      const int gj = J0 - 1 + xc;
      ushort8 u8 = {};
      if (((unsigned)gi < 128u) && ((unsigned)gj < 128u)) {
        const float* p = xb + ((gi << 7) + gj) * 128 + (cp << 3);
        const float4 A = *(const float4*)p;
        const float4 Bv = *(const float4*)(p + 4);
        u8[0] = f2bf(A.x); u8[1] = f2bf(A.y); u8[2] = f2bf(A.z); u8[3] = f2bf(A.w);
        u8[4] = f2bf(Bv.x); u8[5] = f2bf(Bv.y); u8[6] = f2bf(Bv.z); u8[7] = f2bf(Bv.w);
      }
      int byte = (pos << 8) + (cp << 4);
      byte ^= (pos & 7) << 4;  // bank swizzle (write side)
      *(ushort8*)(xlds + byte) = u8;
    }
    __syncthreads();

    // ---- K-loop (R8 proven; b0 rotation wraps to g=0 for the next tile) ----
#pragma unroll 1
    for (int g = 0; g < 12; ++g) {
      const int cblk = (g * 11) >> 5;  // g/3 for g<12
      const int dv = g - cblk * 3;
      const int kbyte = (cblk * 4 + lh) << 4;
      const int pbase = a * 19 + colpart + dv;
      bf16x8 af[10];
      AREADP(0); AREADP(1); AREADP(2); AREADP(3);
      AREADP(4); AREADP(5); AREADP(6); AREADP(7);
      LOADB(b1, g, 1);
      AREADP(8); AREADP(9);
      LOADB(b2, g, 2);
      MFMASP(0, b0);
      {
        const int gn = (g < 11) ? (g + 1) : 0;  // wrap across tiles
        LOADB(b0, gn, 0);
      }
      MFMASP(1, b1);
      MFMASP(2, b2);
    }

    // ---- Epilogue tile t: issue stores (drain under next stage/K-loop) ----
#pragma unroll
    for (int m = 0; m < 8; ++m) {
      const int p = it * 16 + 2 * m + a;
      if (p != 0) {  // wave-uniform; border path owns p==0
#pragma unroll
        for (int jr = 0; jr < 4; ++jr) {
          const int q = jt * 32 + 2 * (lh * 4 + jr) + b;
          if (q == 0) continue;  // border path owns q==0
          float* orow = ob + (p * 256 + q) * 128;
#pragma unroll
          for (int n = 0; n < 4; ++n) orow[n * 16] = acc[m][n][jr] + bv[n];
        }
      }
#pragma unroll
      for (int n = 0; n < 4; ++n) acc[m][n] = (f32x4){0.f, 0.f, 0.f, 0.f};
    }
  }
#undef AREADP
#undef MFMASP
#undef LOADB
}

extern "C" void kernel_launch(void* const* d_in, const int* in_sizes, int n_in,
                              void* d_out, int out_size, void* d_ws, size_t ws_size,
                              hipStream_t stream) {
  const float* x = (const float*)d_in[0];
  const float* w = (const float*)d_in[1];
  const float* bias = (const float*)d_in[2];
  float* out = (float*)d_out;
  unsigned short* pw = (unsigned short*)d_ws;  // 1,179,648 B used

  pack_weights<<<dim3(288), dim3(64), 0, stream>>>(w, pw);
  fused_all<<<dim3(768), dim3(512), 0, stream>>>(x, pw, w, bias, out);
}